// Round 11
// baseline (429.569 us; speedup 1.0000x reference)
//
#include <hip/hip_runtime.h>
#include <math.h>

#define CIN    64
#define OUTC   64
#define BOT    16
#define KK     9
#define HH     48
#define WW     48
#define LPIX   (HH*WW)      // 2304
#define WSZ    9216
#define PSZ    1024
#define PREDCH 10304
#define GRPSZ  2576
#define BATCH  2

// fallback (dppc7) constants
#define NPX    18
#define PXS2   1172
#define DBS    65

typedef __attribute__((ext_vector_type(8)))  short short8v;
typedef __attribute__((ext_vector_type(4)))  float float4v;
typedef __attribute__((ext_vector_type(16))) float float16v;

__device__ inline unsigned short f2bf(float f){
    unsigned u = __float_as_uint(f);
    return (unsigned short)((u + 0x7FFFu + ((u>>16)&1u)) >> 16);   // RNE
}

// ws layout (bytes): Wb bf16 @0; Pws @WB_B; Qws @...; Dyn @...
#define WB_B   329728u                       // 10304*16*2
#define P_B    42467328u                     // 2304*9216*2
#define Q_B    4718592u                      // 2304*1024*2
#define D_B    589824u                       // 2304*64*4
#define NEED   ((size_t)WB_B + P_B + Q_B + D_B)   // 48,105,472

__global__ __launch_bounds__(256) void cvt_wp(const float* __restrict__ Wp,
                                              unsigned short* __restrict__ Wb) {
    const int n = PREDCH * 16;
    for (int i = blockIdx.x * 256 + threadIdx.x; i < n; i += gridDim.x * 256)
        Wb[i] = f2bf(Wp[i]);
}

// ============================ Kernel A: pred GEMM ============================
// grid 288 per batch: 144 px-tiles (16 consecutive px in a row) x 2 ch-halves.
// ch-tiles of 16 NEVER straddle groups (2576 = 161*16) -> single MFMA, no mask.
// P stored [px][m'=t*64+c][d] bf16 (scattered b16 stores, L2-merged);
// Q stored [px][o*16+d] bf16; dyn_b [px][o] f32.  One barrier total.
__global__ __launch_bounds__(256) void predA(
    const float* __restrict__ xb,            // x for this batch
    const unsigned short* __restrict__ Wb,
    const float* __restrict__ bp,
    unsigned short* __restrict__ Pws,
    unsigned short* __restrict__ Qws,
    float* __restrict__ Dyn)
{
    __shared__ unsigned short xcb[16 * 64];  // centers bf16 [px][c], 2 KB

    const int tid  = threadIdx.x;
    const int wave = tid >> 6;
    const int lane = tid & 63;
    const int quad = lane >> 4;
    const int lrow = lane & 15;

    const int bi   = blockIdx.x;
    const int half = bi / 144;
    const int pxt  = bi - half * 144;
    const int h    = pxt / 3;
    const int w0   = (pxt - 3 * (pxt / 3)) * 16;
    const int pxg0 = h * WW + w0;

    // stage centers (coalesced: 16 consecutive px per c)
    for (int i = tid; i < 1024; i += 256) {
        const int c  = i >> 4;
        const int px = i & 15;
        xcb[px * 64 + c] = f2bf(xb[c * LPIX + pxg0 + px]);
    }
    __syncthreads();

    // B-frags (center x), k = c-within-group; bias slot k=16 = 1.0
    short8v Bf[4];
    #pragma unroll
    for (int g = 0; g < 4; ++g) {
        short8v f = (short8v)0;
        if (quad < 2)
            f = *(const short8v*)&xcb[lrow * 64 + g * 16 + quad * 8];
        if (quad == 2) f[0] = (short)0x3F80;
        Bf[g] = f;
    }

    const int pxg = pxg0 + lrow;             // this lane's pixel (D col = lane&15)

    // 644 tiles total (576 P + 64 Q + 4 dynb), split across 2 halves
    for (int i2 = wave; i2 < 322; i2 += 4) {
        const int gt  = half * 322 + i2;
        const int ch0 = gt * 16;
        const int mych = ch0 + lrow;

        short8v a = (short8v)0;
        if (quad < 2)       a = *(const short8v*)(Wb + (size_t)mych * 16 + quad * 8);
        else if (quad == 2) a[0] = (short)f2bf(bp[mych]);

        const int g = gt / 161;              // uniform per tile, no straddle
        float4v Dv = {0.f, 0.f, 0.f, 0.f};
        if      (g == 0) Dv = __builtin_amdgcn_mfma_f32_16x16x32_bf16(a, Bf[0], Dv, 0, 0, 0);
        else if (g == 1) Dv = __builtin_amdgcn_mfma_f32_16x16x32_bf16(a, Bf[1], Dv, 0, 0, 0);
        else if (g == 2) Dv = __builtin_amdgcn_mfma_f32_16x16x32_bf16(a, Bf[2], Dv, 0, 0, 0);
        else             Dv = __builtin_amdgcn_mfma_f32_16x16x32_bf16(a, Bf[3], Dv, 0, 0, 0);

        if (gt < 576) {                      // P part: ch = d*576 + c*9 + t
            const int d  = gt / 36;          // constant per tile
            const int mb = (gt - d * 36) * 16 + quad * 4;
            #pragma unroll
            for (int rr = 0; rr < 4; ++rr) {
                const int m = mb + rr;
                const int c = (m * 7282) >> 16;      // m/9 exact for m<576
                const int t = m - 9 * c;
                Pws[(size_t)pxg * 9216 + ((t << 6) + c) * 16 + d] = f2bf(Dv[rr]);
            }
        } else if (gt < 640) {               // Q part: o = gt-576, d = quad*4+rr
            const int qt = gt - 576;
            uint2 pk;
            pk.x = (unsigned)f2bf(Dv[0]) | ((unsigned)f2bf(Dv[1]) << 16);
            pk.y = (unsigned)f2bf(Dv[2]) | ((unsigned)f2bf(Dv[3]) << 16);
            *(uint2*)(Qws + (size_t)pxg * 1024 + qt * 16 + quad * 4) = pk;
        } else {                             // dyn_b
            const int o0 = (gt - 640) * 16 + quad * 4;
            *(float4*)(Dyn + (size_t)pxg * 64 + o0) =
                make_float4(Dv[0], Dv[1], Dv[2], Dv[3]);
        }
    }
}

// ====================== Kernel B: Y = P^T Q + norm + conv ======================
// grid 288 per batch: px-tiles 2x4. 4 waves, 2 px each. One barrier total.
// 32x32x16 bf16 MFMA: M=c(32 of 64), N=o(32 of 64), K=d=16 exact; all lanes live.
// C/D: col=lane&31, row=(reg&3)+8*(reg>>2)+4*(lane>>5)  [verified m74/m101]
__global__ __launch_bounds__(256) void convB(
    const float* __restrict__ xb,
    const unsigned short* __restrict__ Pws,
    const unsigned short* __restrict__ Qws,
    const float* __restrict__ Dyn,
    float* __restrict__ outb)
{
    __shared__ float xt2[24 * 64];           // [sp(4x6)][c], 6 KB

    const int tid  = threadIdx.x;
    const int wave = tid >> 6;
    const int lane = tid & 63;
    const int hi   = lane >> 5;
    const int n32  = lane & 31;

    const int bi = blockIdx.x;
    const int h0 = (bi / 12) * 2;
    const int w0 = (bi - 12 * (bi / 12)) * 4;

    // stage transposed x window: rows h0-1..h0+2, cols w0-1..w0+4
    for (int i = tid; i < 1536; i += 256) {
        const int c  = i / 24;
        const int sp = i - c * 24;
        const int hh = h0 - 1 + sp / 6;
        const int ww = w0 - 1 + sp % 6;
        float v = 0.0f;
        if (hh >= 0 && hh < HH && ww >= 0 && ww < WW)
            v = xb[c * LPIX + hh * WW + ww];
        xt2[sp * 64 + c] = v;
    }
    __syncthreads();

    #pragma unroll
    for (int p = 0; p < 2; ++p) {
        const int pt   = 2 * wave + p;       // 0..7
        const int prow = pt >> 2, pcol = pt & 3;
        const int pxg  = (h0 + prow) * WW + (w0 + pcol);

        // Q B-frags (const over t): B[k=d][n=o], lane reads Q[o=n32][d=hi*8..]
        const short8v Bq0 = *(const short8v*)(Qws + (size_t)pxg * 1024 + (n32 * 16) + hi * 8);
        const short8v Bq1 = *(const short8v*)(Qws + (size_t)pxg * 1024 + ((32 + n32) * 16) + hi * 8);

        float acc0 = 0.f, acc1 = 0.f;
        for (int t = 0; t < KK; ++t) {
            const int tr = t / 3, tc = t - 3 * (t / 3);
            const float* xrow = &xt2[((prow + tr) * 6 + pcol + tc) * 64];

            float na0 = 0.f, na1 = 0.f, dp0 = 0.f, dp1 = 0.f;
            #pragma unroll
            for (int ch2 = 0; ch2 < 2; ++ch2) {
                // A-frag: A[m'=t*64+ch2*32+n32][d = hi*8 + j]
                const short8v Ap = *(const short8v*)(Pws + (size_t)pxg * 9216
                                        + (size_t)((t * 64 + ch2 * 32 + n32) * 16) + hi * 8);
                float4v pvv[4];
                #pragma unroll
                for (int rg = 0; rg < 4; ++rg)
                    pvv[rg] = *(const float4v*)&xrow[ch2 * 32 + rg * 8 + hi * 4];

                float16v D0 = (float16v)0.f;
                D0 = __builtin_amdgcn_mfma_f32_32x32x16_bf16(Ap, Bq0, D0, 0, 0, 0);
                #pragma unroll
                for (int reg = 0; reg < 16; ++reg) {
                    const float v  = D0[reg];
                    const float pv = pvv[reg >> 2][reg & 3];
                    na0 += v * v;
                    dp0 += pv * v;
                }
                float16v D1 = (float16v)0.f;
                D1 = __builtin_amdgcn_mfma_f32_32x32x16_bf16(Ap, Bq1, D1, 0, 0, 0);
                #pragma unroll
                for (int reg = 0; reg < 16; ++reg) {
                    const float v  = D1[reg];
                    const float pv = pvv[reg >> 2][reg & 3];
                    na1 += v * v;
                    dp1 += pv * v;
                }
            }
            na0 += __shfl_xor(na0, 32);  dp0 += __shfl_xor(dp0, 32);
            na1 += __shfl_xor(na1, 32);  dp1 += __shfl_xor(dp1, 32);
            acc0 += dp0 / fmaxf(sqrtf(fmaxf(na0, 0.f)), 1e-12f);
            acc1 += dp1 / fmaxf(sqrtf(fmaxf(na1, 0.f)), 1e-12f);
        }
        const int o = hi * 32 + n32;
        const float v = (hi ? acc1 : acc0) + Dyn[(size_t)pxg * 64 + o];
        outb[(size_t)o * LPIX + pxg] = v;
    }
}

// ========================= Fallback: dppc7 (100.7 us) =========================
__global__ __launch_bounds__(576, 3) void dppc7f(
    const float* __restrict__ x,
    const unsigned short* __restrict__ Wb,
    const float* __restrict__ bp,
    float* __restrict__ out)
{
    __shared__ float          xt[64 * 5 * 8];
    __shared__ unsigned short S[2][NPX * PXS2];
    __shared__ float          dynb[NPX * DBS];

    const int tid  = threadIdx.x;
    const int wave = tid >> 6;
    const int lane = tid & 63;
    const int quad = lane >> 4;
    const int lrow = lane & 15;

    const int bi = blockIdx.x;
    const int b  = bi >> 7;
    const int r  = bi & 127;
    const int h0 = (r >> 3) * 3;
    const int w0 = (r & 7) * 6;

    const float* xb = x + (size_t)b * CIN * LPIX;
    for (int i = tid; i < 64 * 5 * 8; i += 576) {
        const int c  = i / 40;
        const int rm = i - c * 40;
        const int hi = h0 - 1 + (rm >> 3);
        const int wi = w0 - 1 + (rm & 7);
        float v = 0.0f;
        if (hi >= 0 && hi < HH && wi >= 0 && wi < WW)
            v = xb[c * LPIX + hi * WW + wi];
        xt[i] = v;
    }
    __syncthreads();

    short8v Bf[4][2];
    #pragma unroll
    for (int g = 0; g < 4; ++g) {
        #pragma unroll
        for (int nt = 0; nt < 2; ++nt) {
            const int px = nt * 16 + lrow;
            short8v f = (short8v)0;
            if (quad < 2 && px < NPX) {
                const int pr = px / 6, pc = px - 6 * (px / 6);
                #pragma unroll
                for (int j = 0; j < 8; ++j)
                    f[j] = (short)f2bf(xt[((g * 16 + quad * 8 + j) * 5 + pr + 1) * 8 + pc + 1]);
            }
            if (quad == 2 && px < NPX) f[0] = (short)0x3F80;
            Bf[g][nt] = f;
        }
    }

    for (int u = wave; u < 68; u += 9) {
        const int ch0  = WSZ + u * 16;
        const int mych = ch0 + lrow;
        short8v a = (short8v)0;
        if (quad < 2)       a = *(const short8v*)(Wb + (size_t)mych * 16 + quad * 8);
        else if (quad == 2) a[0] = (short)f2bf(bp[mych]);
        #pragma unroll
        for (int nt = 0; nt < 2; ++nt) {
            float4v Dv = {0.f, 0.f, 0.f, 0.f};
            Dv = __builtin_amdgcn_mfma_f32_16x16x32_bf16(a, Bf[3][nt], Dv, 0, 0, 0);
            const int px = nt * 16 + lrow;
            if (px < NPX) {
                #pragma unroll
                for (int rr = 0; rr < 4; ++rr) {
                    const int ch = ch0 + quad * 4 + rr;
                    if (ch < WSZ + PSZ) {
                        const int i = ch - WSZ;
                        S[0][px * PXS2 + (i >> 4) * 18 + (i & 15)] = f2bf(Dv[rr]);
                    } else {
                        dynb[px * DBS + (ch - WSZ - PSZ)] = Dv[rr];
                    }
                }
            }
        }
    }
    __syncthreads();

    const int pxA = 2 * wave;
    const int pxB = 2 * wave + 1;
    short8v Bq[2][4];
    #pragma unroll
    for (int p = 0; p < 2; ++p) {
        const int px = 2 * wave + p;
        #pragma unroll
        for (int Nt = 0; Nt < 4; ++Nt) {
            short8v f = (short8v)0;
            if (quad < 2)
                f = *(const short8v*)&S[0][px * PXS2 + (Nt * 16 + lrow) * 18 + quad * 8];
            Bq[p][Nt] = f;
        }
    }
    __syncthreads();

    float acc[2][4] = {};

    #define FB_PASS(GG, NT)                                                           \
        { short8v am = (myg == (GG)) ? a : (short8v)0;                                \
          Dv = __builtin_amdgcn_mfma_f32_16x16x32_bf16(am, Bf[GG][NT], Dv, 0, 0, 0); }

    #define FB_PRED(T, BUF)                                                           \
    for (int u = wave; u < 64; u += 9) {                                              \
        const int d  = u >> 2;                                                        \
        const int c0 = (u & 3) * 16;                                                  \
        const int ch0  = d * 576 + c0 * 9 + (T);                                      \
        const int mych = ch0 + 9 * lrow;                                              \
        short8v a = (short8v)0;                                                       \
        if (quad < 2)       a = *(const short8v*)(Wb + (size_t)mych * 16 + quad * 8); \
        else if (quad == 2) a[0] = (short)f2bf(bp[mych]);                             \
        const int g0  = ch0 / GRPSZ;                                                  \
        const int g1  = (ch0 + 135) / GRPSZ;                                          \
        const int myg = mych / GRPSZ;                                                 \
        _Pragma("unroll")                                                             \
        for (int nt = 0; nt < 2; ++nt) {                                              \
            float4v Dv = {0.f, 0.f, 0.f, 0.f};                                        \
            if (g0 == 0)      { FB_PASS(0, nt) if (g1 == 1) FB_PASS(1, nt) }          \
            else if (g0 == 1) { FB_PASS(1, nt) if (g1 == 2) FB_PASS(2, nt) }          \
            else if (g0 == 2) { FB_PASS(2, nt) if (g1 == 3) FB_PASS(3, nt) }          \
            else              { FB_PASS(3, nt) }                                      \
            const int px = nt * 16 + lrow;                                            \
            if (px < NPX) {                                                           \
                _Pragma("unroll")                                                     \
                for (int rr = 0; rr < 4; ++rr)                                        \
                    S[BUF][px * PXS2 + (c0 + quad * 4 + rr) * 18 + d] = f2bf(Dv[rr]); \
            }                                                                         \
        }                                                                             \
    }

    FB_PRED(0, 0)
    __syncthreads();

    for (int t = 0; t < KK; ++t) {
        const int buf = t & 1;
        if (t < 8) { FB_PRED(t + 1, (t + 1) & 1) }

        const int tr = t / 3, tc = t - 3 * (t / 3);
        #pragma unroll
        for (int p = 0; p < 2; ++p) {
            const int px = (p == 0) ? pxA : pxB;
            const int pr = px / 6, pc = px - 6 * (px / 6);

            short8v Ap[4];
            #pragma unroll
            for (int Mt = 0; Mt < 4; ++Mt) {
                short8v f = (short8v)0;
                if (quad < 2)
                    f = *(const short8v*)&S[buf][px * PXS2 + (Mt * 16 + lrow) * 18 + quad * 8];
                Ap[Mt] = f;
            }
            float pv[4][4];
            #pragma unroll
            for (int Mt = 0; Mt < 4; ++Mt)
                #pragma unroll
                for (int rr = 0; rr < 4; ++rr) {
                    const int c = Mt * 16 + quad * 4 + rr;
                    pv[Mt][rr] = xt[(c * 5 + pr + tr) * 8 + pc + tc];
                }

            #pragma unroll
            for (int Nt = 0; Nt < 4; ++Nt) {
                float nacc = 0.f, dpacc = 0.f;
                #pragma unroll
                for (int Mt = 0; Mt < 4; ++Mt) {
                    float4v Dv = {0.f, 0.f, 0.f, 0.f};
                    Dv = __builtin_amdgcn_mfma_f32_16x16x32_bf16(Ap[Mt], Bq[p][Nt], Dv, 0, 0, 0);
                    #pragma unroll
                    for (int rr = 0; rr < 4; ++rr) {
                        nacc  += Dv[rr] * Dv[rr];
                        dpacc += pv[Mt][rr] * Dv[rr];
                    }
                }
                nacc  += __shfl_xor(nacc, 16);  nacc  += __shfl_xor(nacc, 32);
                dpacc += __shfl_xor(dpacc, 16); dpacc += __shfl_xor(dpacc, 32);
                acc[p][Nt] += dpacc / fmaxf(sqrtf(fmaxf(nacc, 0.f)), 1e-12f);
            }
        }
        __syncthreads();
    }

    if (quad == 0) {
        #pragma unroll
        for (int p = 0; p < 2; ++p) {
            const int px = (p == 0) ? pxA : pxB;
            const int pr = px / 6, pc = px - 6 * (px / 6);
            const int l  = (h0 + pr) * WW + (w0 + pc);
            #pragma unroll
            for (int Nt = 0; Nt < 4; ++Nt) {
                const int o = Nt * 16 + lrow;
                out[((size_t)b * OUTC + o) * LPIX + l] = acc[p][Nt] + dynb[px * DBS + o];
            }
        }
    }
}

extern "C" void kernel_launch(void* const* d_in, const int* in_sizes, int n_in,
                              void* d_out, int out_size, void* d_ws, size_t ws_size,
                              hipStream_t stream) {
    const float* x  = (const float*)d_in[0];
    const float* Wp = (const float*)d_in[1];
    const float* bp = (const float*)d_in[2];
    float* out = (float*)d_out;
    (void)in_sizes; (void)n_in; (void)out_size;

    char* w = (char*)d_ws;
    unsigned short* Wb = (unsigned short*)w;

    hipLaunchKernelGGL(cvt_wp, dim3(160), dim3(256), 0, stream, Wp, Wb);

    if (ws_size >= NEED) {
        unsigned short* Pws = (unsigned short*)(w + WB_B);
        unsigned short* Qws = (unsigned short*)(w + WB_B + P_B);
        float*          Dyn = (float*)(w + WB_B + P_B + Q_B);
        for (int b = 0; b < BATCH; ++b) {
            const float* xb   = x + (size_t)b * CIN * LPIX;
            float*       outb = out + (size_t)b * OUTC * LPIX;
            hipLaunchKernelGGL(predA, dim3(288), dim3(256), 0, stream,
                               xb, Wb, bp, Pws, Qws, Dyn);
            hipLaunchKernelGGL(convB, dim3(288), dim3(256), 0, stream,
                               xb, Pws, Qws, Dyn, outb);
        }
    } else {
        hipLaunchKernelGGL(dppc7f, dim3(BATCH * 128), dim3(576), 0, stream, x, Wb, bp, out);
    }
}

// Round 12
// 206.775 us; speedup vs baseline: 2.0775x; 2.0775x over previous
//
#include <hip/hip_runtime.h>
#include <math.h>

#define CIN    64
#define OUTC   64
#define BOT    16
#define KK     9
#define HH     48
#define WW     48
#define LPIX   (HH*WW)      // 2304
#define WSZ    9216
#define PSZ    1024
#define PREDCH 10304
#define GRPSZ  2576
#define BATCH  2

// fallback (dppc7) constants
#define NPX    18
#define PXS2   1172
#define DBS    65

typedef __attribute__((ext_vector_type(8)))  short short8v;
typedef __attribute__((ext_vector_type(4)))  float float4v;
typedef __attribute__((ext_vector_type(16))) float float16v;

__device__ inline unsigned short f2bf(float f){
    unsigned u = __float_as_uint(f);
    return (unsigned short)((u + 0x7FFFu + ((u>>16)&1u)) >> 16);   // RNE
}

// ws layout (bytes): Wb | Wa | bpT | Pws | Qws | Dyn
#define WB_B   329728u                        // 10304*16*2   (fallback)
#define WA_B   659456u                        // 10304*32*2   (2-group-packed A)
#define BPT_B  36864u                         // 576*16*4     (bias transposed [s][d])
#define P_B    42467328u                      // 2304*9216*2
#define Q_B    4718592u                       // 2304*1024*2
#define D_B    589824u                        // 2304*64*4
#define NEED   ((size_t)WB_B + WA_B + BPT_B + P_B + Q_B + D_B)   // 48,801,792

// prep: Wb (fallback), Wa (slot-half g&1 placement, zeros elsewhere), bpT.
__global__ __launch_bounds__(256) void prep(const float* __restrict__ Wp,
                                            const float* __restrict__ bp,
                                            unsigned short* __restrict__ Wb,
                                            unsigned short* __restrict__ Wa,
                                            float* __restrict__ bpT,
                                            int full) {
    const int n1 = PREDCH * 16;
    const int n2 = PREDCH * 32;
    const int i  = blockIdx.x * 256 + threadIdx.x;
    if (i < n1) {
        Wb[i] = f2bf(Wp[i]);
    } else if (full) {
        if (i < n1 + n2) {
            const int j  = i - n1;
            const int ch = j >> 5;
            const int k  = j & 31;
            const int g  = ch / GRPSZ;
            Wa[j] = ((k >> 4) == (g & 1)) ? f2bf(Wp[ch * 16 + (k & 15)])
                                          : (unsigned short)0;
        } else if (i < n1 + n2 + 9216) {
            const int j = i - n1 - n2;          // j = s*16 + d
            const int d = j & 15;
            const int s = j >> 4;
            bpT[j] = bp[576 * d + s];
        }
    }
}

// ===================== Kernel A v2: pred GEMM, d as M-dim =====================
// Block = 16 px (one row chunk) x half of 644 tiles. 256 thr (4 waves).
// P-tile (c,t): rows ch = 576*d + c*9 + t, d=0..15.  D[d][px]: lane(q,l) holds
// px=l, d=4q..4q+3 -> ONE uint2 store to Pws[px][m'=t*64+c][d] (transpose-free).
// Wa 2-group packing: 2 masked MFMAs (B = x[0..31], x[32..63]); bias via C-init.
__global__ __launch_bounds__(256) void predA2(
    const float* __restrict__ xb,
    const unsigned short* __restrict__ Wa,
    const float* __restrict__ bp,
    const float* __restrict__ bpT,
    unsigned short* __restrict__ Pws,
    unsigned short* __restrict__ Qws,
    float* __restrict__ Dyn)
{
    __shared__ unsigned short xcb[16 * 64];   // centers bf16 [px][c], 2 KB

    const int tid  = threadIdx.x;
    const int wave = tid >> 6;
    const int lane = tid & 63;
    const int quad = lane >> 4;
    const int lrow = lane & 15;

    const int bi   = blockIdx.x;
    const int half = bi / 144;
    const int pxt  = bi - half * 144;
    const int h    = pxt / 3;
    const int w0   = (pxt - 3 * (pxt / 3)) * 16;
    const int pxg0 = h * WW + w0;

    for (int i = tid; i < 1024; i += 256) {
        const int c  = i >> 4;
        const int px = i & 15;
        xcb[px * 64 + c] = f2bf(xb[c * LPIX + pxg0 + px]);
    }
    __syncthreads();

    // B-frags: B[k=quad*8+j][n=lrow=px]; Blo = x[0..31], Bhi = x[32..63]
    const short8v Blo = *(const short8v*)&xcb[lrow * 64 + quad * 8];
    const short8v Bhi = *(const short8v*)&xcb[lrow * 64 + 32 + quad * 8];

    const size_t pxg = (size_t)(pxg0 + lrow);   // this lane's pixel (D col)

    for (int u = wave; u < 322; u += 4) {
        const int gt = half * 322 + u;
        if (gt < 576) {                       // P-tile: c,t; m' = gt
            const int c = gt & 63;
            const int t = gt >> 6;
            const int s = c * 9 + t;
            const int mych = 576 * lrow + s;  // this lane's A-row (d = lrow)
            const short8v a = *(const short8v*)(Wa + (size_t)mych * 32 + quad * 8);
            float4v Dv = *(const float4v*)(bpT + s * 16 + quad * 4);
            const short8v alo = (mych < 2 * GRPSZ) ? a : (short8v)0;
            const short8v ahi = (mych < 2 * GRPSZ) ? (short8v)0 : a;
            Dv = __builtin_amdgcn_mfma_f32_16x16x32_bf16(alo, Blo, Dv, 0, 0, 0);
            Dv = __builtin_amdgcn_mfma_f32_16x16x32_bf16(ahi, Bhi, Dv, 0, 0, 0);
            uint2 pk;
            pk.x = (unsigned)f2bf(Dv[0]) | ((unsigned)f2bf(Dv[1]) << 16);
            pk.y = (unsigned)f2bf(Dv[2]) | ((unsigned)f2bf(Dv[3]) << 16);
            *(uint2*)(Pws + pxg * 9216 + gt * 16 + quad * 4) = pk;
        } else if (gt < 640) {                // Q-tile: rows = d (j), fixed o
            const int o = gt - 576;
            const int mych = WSZ + o * 16 + lrow;          // g=3: Wa slots 16-31
            const short8v a = *(const short8v*)(Wa + (size_t)mych * 32 + quad * 8);
            float4v Dv = *(const float4v*)(bp + WSZ + o * 16 + quad * 4);
            Dv = __builtin_amdgcn_mfma_f32_16x16x32_bf16(a, Bhi, Dv, 0, 0, 0);
            uint2 pk;
            pk.x = (unsigned)f2bf(Dv[0]) | ((unsigned)f2bf(Dv[1]) << 16);
            pk.y = (unsigned)f2bf(Dv[2]) | ((unsigned)f2bf(Dv[3]) << 16);
            *(uint2*)(Qws + pxg * 1024 + o * 16 + quad * 4) = pk;
        } else {                              // dynb-tile: rows = o
            const int o0 = (gt - 640) * 16;
            const int mych = WSZ + PSZ + o0 + lrow;        // g=3
            const short8v a = *(const short8v*)(Wa + (size_t)mych * 32 + quad * 8);
            float4v Dv = *(const float4v*)(bp + WSZ + PSZ + o0 + quad * 4);
            Dv = __builtin_amdgcn_mfma_f32_16x16x32_bf16(a, Bhi, Dv, 0, 0, 0);
            *(float4*)(Dyn + pxg * 64 + o0 + quad * 4) =
                make_float4(Dv[0], Dv[1], Dv[2], Dv[3]);
        }
    }
}

// ====================== Kernel B: Y = P^T Q + norm + conv ======================
// (unchanged from R11 — verified correct; coalesced 2KB A-chunk reads)
__global__ __launch_bounds__(256) void convB(
    const float* __restrict__ xb,
    const unsigned short* __restrict__ Pws,
    const unsigned short* __restrict__ Qws,
    const float* __restrict__ Dyn,
    float* __restrict__ outb)
{
    __shared__ float xt2[24 * 64];

    const int tid  = threadIdx.x;
    const int wave = tid >> 6;
    const int lane = tid & 63;
    const int hi   = lane >> 5;
    const int n32  = lane & 31;

    const int bi = blockIdx.x;
    const int h0 = (bi / 12) * 2;
    const int w0 = (bi - 12 * (bi / 12)) * 4;

    for (int i = tid; i < 1536; i += 256) {
        const int c  = i / 24;
        const int sp = i - c * 24;
        const int hh = h0 - 1 + sp / 6;
        const int ww = w0 - 1 + sp % 6;
        float v = 0.0f;
        if (hh >= 0 && hh < HH && ww >= 0 && ww < WW)
            v = xb[c * LPIX + hh * WW + ww];
        xt2[sp * 64 + c] = v;
    }
    __syncthreads();

    #pragma unroll
    for (int p = 0; p < 2; ++p) {
        const int pt   = 2 * wave + p;
        const int prow = pt >> 2, pcol = pt & 3;
        const int pxg  = (h0 + prow) * WW + (w0 + pcol);

        const short8v Bq0 = *(const short8v*)(Qws + (size_t)pxg * 1024 + (n32 * 16) + hi * 8);
        const short8v Bq1 = *(const short8v*)(Qws + (size_t)pxg * 1024 + ((32 + n32) * 16) + hi * 8);

        float acc0 = 0.f, acc1 = 0.f;
        for (int t = 0; t < KK; ++t) {
            const int tr = t / 3, tc = t - 3 * (t / 3);
            const float* xrow = &xt2[((prow + tr) * 6 + pcol + tc) * 64];

            float na0 = 0.f, na1 = 0.f, dp0 = 0.f, dp1 = 0.f;
            #pragma unroll
            for (int ch2 = 0; ch2 < 2; ++ch2) {
                const short8v Ap = *(const short8v*)(Pws + (size_t)pxg * 9216
                                        + (size_t)((t * 64 + ch2 * 32 + n32) * 16) + hi * 8);
                float4v pvv[4];
                #pragma unroll
                for (int rg = 0; rg < 4; ++rg)
                    pvv[rg] = *(const float4v*)&xrow[ch2 * 32 + rg * 8 + hi * 4];

                float16v D0 = (float16v)0.f;
                D0 = __builtin_amdgcn_mfma_f32_32x32x16_bf16(Ap, Bq0, D0, 0, 0, 0);
                #pragma unroll
                for (int reg = 0; reg < 16; ++reg) {
                    const float v  = D0[reg];
                    const float pv = pvv[reg >> 2][reg & 3];
                    na0 += v * v;
                    dp0 += pv * v;
                }
                float16v D1 = (float16v)0.f;
                D1 = __builtin_amdgcn_mfma_f32_32x32x16_bf16(Ap, Bq1, D1, 0, 0, 0);
                #pragma unroll
                for (int reg = 0; reg < 16; ++reg) {
                    const float v  = D1[reg];
                    const float pv = pvv[reg >> 2][reg & 3];
                    na1 += v * v;
                    dp1 += pv * v;
                }
            }
            na0 += __shfl_xor(na0, 32);  dp0 += __shfl_xor(dp0, 32);
            na1 += __shfl_xor(na1, 32);  dp1 += __shfl_xor(dp1, 32);
            acc0 += dp0 / fmaxf(sqrtf(fmaxf(na0, 0.f)), 1e-12f);
            acc1 += dp1 / fmaxf(sqrtf(fmaxf(na1, 0.f)), 1e-12f);
        }
        const int o = hi * 32 + n32;
        const float v = (hi ? acc1 : acc0) + Dyn[(size_t)pxg * 64 + o];
        outb[(size_t)o * LPIX + pxg] = v;
    }
}

// ========================= Fallback: dppc7 (100.7 us) =========================
__global__ __launch_bounds__(576, 3) void dppc7f(
    const float* __restrict__ x,
    const unsigned short* __restrict__ Wb,
    const float* __restrict__ bp,
    float* __restrict__ out)
{
    __shared__ float          xt[64 * 5 * 8];
    __shared__ unsigned short S[2][NPX * PXS2];
    __shared__ float          dynb[NPX * DBS];

    const int tid  = threadIdx.x;
    const int wave = tid >> 6;
    const int lane = tid & 63;
    const int quad = lane >> 4;
    const int lrow = lane & 15;

    const int bi = blockIdx.x;
    const int b  = bi >> 7;
    const int r  = bi & 127;
    const int h0 = (r >> 3) * 3;
    const int w0 = (r & 7) * 6;

    const float* xb = x + (size_t)b * CIN * LPIX;
    for (int i = tid; i < 64 * 5 * 8; i += 576) {
        const int c  = i / 40;
        const int rm = i - c * 40;
        const int hi = h0 - 1 + (rm >> 3);
        const int wi = w0 - 1 + (rm & 7);
        float v = 0.0f;
        if (hi >= 0 && hi < HH && wi >= 0 && wi < WW)
            v = xb[c * LPIX + hi * WW + wi];
        xt[i] = v;
    }
    __syncthreads();

    short8v Bf[4][2];
    #pragma unroll
    for (int g = 0; g < 4; ++g) {
        #pragma unroll
        for (int nt = 0; nt < 2; ++nt) {
            const int px = nt * 16 + lrow;
            short8v f = (short8v)0;
            if (quad < 2 && px < NPX) {
                const int pr = px / 6, pc = px - 6 * (px / 6);
                #pragma unroll
                for (int j = 0; j < 8; ++j)
                    f[j] = (short)f2bf(xt[((g * 16 + quad * 8 + j) * 5 + pr + 1) * 8 + pc + 1]);
            }
            if (quad == 2 && px < NPX) f[0] = (short)0x3F80;
            Bf[g][nt] = f;
        }
    }

    for (int u = wave; u < 68; u += 9) {
        const int ch0  = WSZ + u * 16;
        const int mych = ch0 + lrow;
        short8v a = (short8v)0;
        if (quad < 2)       a = *(const short8v*)(Wb + (size_t)mych * 16 + quad * 8);
        else if (quad == 2) a[0] = (short)f2bf(bp[mych]);
        #pragma unroll
        for (int nt = 0; nt < 2; ++nt) {
            float4v Dv = {0.f, 0.f, 0.f, 0.f};
            Dv = __builtin_amdgcn_mfma_f32_16x16x32_bf16(a, Bf[3][nt], Dv, 0, 0, 0);
            const int px = nt * 16 + lrow;
            if (px < NPX) {
                #pragma unroll
                for (int rr = 0; rr < 4; ++rr) {
                    const int ch = ch0 + quad * 4 + rr;
                    if (ch < WSZ + PSZ) {
                        const int i = ch - WSZ;
                        S[0][px * PXS2 + (i >> 4) * 18 + (i & 15)] = f2bf(Dv[rr]);
                    } else {
                        dynb[px * DBS + (ch - WSZ - PSZ)] = Dv[rr];
                    }
                }
            }
        }
    }
    __syncthreads();

    const int pxA = 2 * wave;
    const int pxB = 2 * wave + 1;
    short8v Bq[2][4];
    #pragma unroll
    for (int p = 0; p < 2; ++p) {
        const int px = 2 * wave + p;
        #pragma unroll
        for (int Nt = 0; Nt < 4; ++Nt) {
            short8v f = (short8v)0;
            if (quad < 2)
                f = *(const short8v*)&S[0][px * PXS2 + (Nt * 16 + lrow) * 18 + quad * 8];
            Bq[p][Nt] = f;
        }
    }
    __syncthreads();

    float acc[2][4] = {};

    #define FB_PASS(GG, NT)                                                           \
        { short8v am = (myg == (GG)) ? a : (short8v)0;                                \
          Dv = __builtin_amdgcn_mfma_f32_16x16x32_bf16(am, Bf[GG][NT], Dv, 0, 0, 0); }

    #define FB_PRED(T, BUF)                                                           \
    for (int u = wave; u < 64; u += 9) {                                              \
        const int d  = u >> 2;                                                        \
        const int c0 = (u & 3) * 16;                                                  \
        const int ch0  = d * 576 + c0 * 9 + (T);                                      \
        const int mych = ch0 + 9 * lrow;                                              \
        short8v a = (short8v)0;                                                       \
        if (quad < 2)       a = *(const short8v*)(Wb + (size_t)mych * 16 + quad * 8); \
        else if (quad == 2) a[0] = (short)f2bf(bp[mych]);                             \
        const int g0  = ch0 / GRPSZ;                                                  \
        const int g1  = (ch0 + 135) / GRPSZ;                                          \
        const int myg = mych / GRPSZ;                                                 \
        _Pragma("unroll")                                                             \
        for (int nt = 0; nt < 2; ++nt) {                                              \
            float4v Dv = {0.f, 0.f, 0.f, 0.f};                                        \
            if (g0 == 0)      { FB_PASS(0, nt) if (g1 == 1) FB_PASS(1, nt) }          \
            else if (g0 == 1) { FB_PASS(1, nt) if (g1 == 2) FB_PASS(2, nt) }          \
            else if (g0 == 2) { FB_PASS(2, nt) if (g1 == 3) FB_PASS(3, nt) }          \
            else              { FB_PASS(3, nt) }                                      \
            const int px = nt * 16 + lrow;                                            \
            if (px < NPX) {                                                           \
                _Pragma("unroll")                                                     \
                for (int rr = 0; rr < 4; ++rr)                                        \
                    S[BUF][px * PXS2 + (c0 + quad * 4 + rr) * 18 + d] = f2bf(Dv[rr]); \
            }                                                                         \
        }                                                                             \
    }

    FB_PRED(0, 0)
    __syncthreads();

    for (int t = 0; t < KK; ++t) {
        const int buf = t & 1;
        if (t < 8) { FB_PRED(t + 1, (t + 1) & 1) }

        const int tr = t / 3, tc = t - 3 * (t / 3);
        #pragma unroll
        for (int p = 0; p < 2; ++p) {
            const int px = (p == 0) ? pxA : pxB;
            const int pr = px / 6, pc = px - 6 * (px / 6);

            short8v Ap[4];
            #pragma unroll
            for (int Mt = 0; Mt < 4; ++Mt) {
                short8v f = (short8v)0;
                if (quad < 2)
                    f = *(const short8v*)&S[buf][px * PXS2 + (Mt * 16 + lrow) * 18 + quad * 8];
                Ap[Mt] = f;
            }
            float pv[4][4];
            #pragma unroll
            for (int Mt = 0; Mt < 4; ++Mt)
                #pragma unroll
                for (int rr = 0; rr < 4; ++rr) {
                    const int c = Mt * 16 + quad * 4 + rr;
                    pv[Mt][rr] = xt[(c * 5 + pr + tr) * 8 + pc + tc];
                }

            #pragma unroll
            for (int Nt = 0; Nt < 4; ++Nt) {
                float nacc = 0.f, dpacc = 0.f;
                #pragma unroll
                for (int Mt = 0; Mt < 4; ++Mt) {
                    float4v Dv = {0.f, 0.f, 0.f, 0.f};
                    Dv = __builtin_amdgcn_mfma_f32_16x16x32_bf16(Ap[Mt], Bq[p][Nt], Dv, 0, 0, 0);
                    #pragma unroll
                    for (int rr = 0; rr < 4; ++rr) {
                        nacc  += Dv[rr] * Dv[rr];
                        dpacc += pv[Mt][rr] * Dv[rr];
                    }
                }
                nacc  += __shfl_xor(nacc, 16);  nacc  += __shfl_xor(nacc, 32);
                dpacc += __shfl_xor(dpacc, 16); dpacc += __shfl_xor(dpacc, 32);
                acc[p][Nt] += dpacc / fmaxf(sqrtf(fmaxf(nacc, 0.f)), 1e-12f);
            }
        }
        __syncthreads();
    }

    if (quad == 0) {
        #pragma unroll
        for (int p = 0; p < 2; ++p) {
            const int px = (p == 0) ? pxA : pxB;
            const int pr = px / 6, pc = px - 6 * (px / 6);
            const int l  = (h0 + pr) * WW + (w0 + pc);
            #pragma unroll
            for (int Nt = 0; Nt < 4; ++Nt) {
                const int o = Nt * 16 + lrow;
                out[((size_t)b * OUTC + o) * LPIX + l] = acc[p][Nt] + dynb[px * DBS + o];
            }
        }
    }
}

extern "C" void kernel_launch(void* const* d_in, const int* in_sizes, int n_in,
                              void* d_out, int out_size, void* d_ws, size_t ws_size,
                              hipStream_t stream) {
    const float* x  = (const float*)d_in[0];
    const float* Wp = (const float*)d_in[1];
    const float* bp = (const float*)d_in[2];
    float* out = (float*)d_out;
    (void)in_sizes; (void)n_in; (void)out_size;

    char* w = (char*)d_ws;
    unsigned short* Wb  = (unsigned short*)w;
    unsigned short* Wa  = (unsigned short*)(w + WB_B);
    float*          bpT = (float*)(w + WB_B + WA_B);
    unsigned short* Pws = (unsigned short*)(w + WB_B + WA_B + BPT_B);
    unsigned short* Qws = (unsigned short*)(w + WB_B + WA_B + BPT_B + P_B);
    float*          Dyn = (float*)(w + WB_B + WA_B + BPT_B + P_B + Q_B);

    const int full = (ws_size >= NEED) ? 1 : 0;
    const int nprep = PREDCH * 16 + PREDCH * 32 + 9216;
    hipLaunchKernelGGL(prep, dim3((nprep + 255) / 256), dim3(256), 0, stream,
                       Wp, bp, Wb, Wa, bpT, full);

    if (full) {
        for (int b = 0; b < BATCH; ++b) {
            const float* xb   = x + (size_t)b * CIN * LPIX;
            float*       outb = out + (size_t)b * OUTC * LPIX;
            hipLaunchKernelGGL(predA2, dim3(288), dim3(256), 0, stream,
                               xb, Wa, bp, bpT, Pws, Qws, Dyn);
            hipLaunchKernelGGL(convB, dim3(288), dim3(256), 0, stream,
                               xb, Pws, Qws, Dyn, outb);
        }
    } else {
        hipLaunchKernelGGL(dppc7f, dim3(BATCH * 128), dim3(576), 0, stream, x, Wb, bp, out);
    }
}